// Round 1
// baseline (538.237 us; speedup 1.0000x reference)
//
#include <hip/hip_runtime.h>
#include <hip/hip_bf16.h>
#include <stdint.h>
#include <math.h>

#define B_ 4
#define T_ 2048
#define E_ 1024
#define H_ 16
#define D_ 64

typedef __attribute__((ext_vector_type(8))) short short8;
typedef __attribute__((ext_vector_type(4))) float f32x4;

#define MFMA_BF16(a, b, c) __builtin_amdgcn_mfma_f32_16x16x32_bf16((a), (b), (c), 0, 0, 0)

__device__ __forceinline__ unsigned short f2bf(float f) {
  union { float f; unsigned u; } v; v.f = f;
  unsigned r = v.u + 0x7FFFu + ((v.u >> 16) & 1u);  // RNE
  return (unsigned short)(r >> 16);
}

#define GLOAD_LDS16(g, l)                                                        \
  __builtin_amdgcn_global_load_lds((const __attribute__((address_space(1))) void*)(g), \
                                   (__attribute__((address_space(3))) void*)(l), 16, 0, 0)

// ---------------- fp32 -> bf16 convert (vectorized) ----------------
__global__ __launch_bounds__(256) void cvt_f32_bf16(const float* __restrict__ in,
                                                    unsigned short* __restrict__ out,
                                                    int n8) {
  int i = blockIdx.x * blockDim.x + threadIdx.x;
  if (i >= n8) return;
  const float4* p = (const float4*)(in + (size_t)i * 8);
  float4 a = p[0], b = p[1];
  short8 r;
  r[0] = (short)f2bf(a.x); r[1] = (short)f2bf(a.y);
  r[2] = (short)f2bf(a.z); r[3] = (short)f2bf(a.w);
  r[4] = (short)f2bf(b.x); r[5] = (short)f2bf(b.y);
  r[6] = (short)f2bf(b.z); r[7] = (short)f2bf(b.w);
  *(short8*)(out + (size_t)i * 8) = r;
}

// ---------------- GEMM: C[M,N] = A[M,K] * B[N,K]^T (bf16 in, MODE-dep out) ----
// MODE 0: write bf16 to [B,H,T,D] (row m = b*T+t, col n = h*D+d)
// MODE 1: write fp32 row-major [M,N] + bias[n]
template <int MODE>
__global__ __launch_bounds__(256) void gemm_bt(const unsigned short* __restrict__ A,
                                               const unsigned short* __restrict__ Bm,
                                               void* __restrict__ outp,
                                               const float* __restrict__ bias,
                                               int M, int N, int K) {
  __shared__ __align__(16) unsigned short Ab[128 * 64];
  __shared__ __align__(16) unsigned short Bb[128 * 64];
  const int tid = threadIdx.x;
  const int wid = tid >> 6;
  const int lr = tid & 15;        // lane & 15
  const int lk = (tid >> 4) & 3;  // lane >> 4
  const int wr = wid >> 1, wc = wid & 1;
  const int m0 = blockIdx.x * 128, n0 = blockIdx.y * 128;

  f32x4 acc[4][4] = {};

  for (int k0 = 0; k0 < K; k0 += 64) {
    __syncthreads();
#pragma unroll
    for (int pass = 0; pass < 4; ++pass) {
      int chunk = pass * 256 + tid;
      int row = chunk >> 3, inner = chunk & 7;
      const unsigned short* ga = A + (size_t)(m0 + row) * K + k0 + inner * 8;
      const unsigned short* gb = Bm + (size_t)(n0 + row) * K + k0 + inner * 8;
      unsigned short* la = Ab + (size_t)(pass * 256 + wid * 64) * 8;  // wave-uniform base
      unsigned short* lb = Bb + (size_t)(pass * 256 + wid * 64) * 8;
      GLOAD_LDS16(ga, la);
      GLOAD_LDS16(gb, lb);
    }
    __syncthreads();
#pragma unroll
    for (int kk = 0; kk < 2; ++kk) {
      short8 af[4], bf[4];
#pragma unroll
      for (int mi = 0; mi < 4; ++mi)
        af[mi] = *(const short8*)&Ab[(wr * 64 + mi * 16 + lr) * 64 + kk * 32 + lk * 8];
#pragma unroll
      for (int ni = 0; ni < 4; ++ni)
        bf[ni] = *(const short8*)&Bb[(wc * 64 + ni * 16 + lr) * 64 + kk * 32 + lk * 8];
#pragma unroll
      for (int mi = 0; mi < 4; ++mi)
#pragma unroll
        for (int ni = 0; ni < 4; ++ni)
          acc[mi][ni] = MFMA_BF16(af[mi], bf[ni], acc[mi][ni]);
    }
  }

#pragma unroll
  for (int mi = 0; mi < 4; ++mi) {
#pragma unroll
    for (int ni = 0; ni < 4; ++ni) {
#pragma unroll
      for (int r = 0; r < 4; ++r) {
        int row = m0 + wr * 64 + mi * 16 + lk * 4 + r;
        int col = n0 + wc * 64 + ni * 16 + lr;
        float v = acc[mi][ni][r];
        if (MODE == 0) {
          int b = row >> 11, t = row & (T_ - 1), h = col >> 6, d = col & (D_ - 1);
          ((unsigned short*)outp)[(((size_t)(b * H_ + h)) * T_ + t) * D_ + d] = f2bf(v);
        } else {
          ((float*)outp)[(size_t)row * N + col] = v + bias[col];
        }
      }
    }
  }
}

// ---------------- fused causal flash attention ----------------
// Q,K,V bf16 [B*H, T, D]; ctx bf16 [B*T, E] (col = h*D+d). One block = (qb, bh).
__global__ __launch_bounds__(256) void attn_fused(const unsigned short* __restrict__ Q,
                                                  const unsigned short* __restrict__ K,
                                                  const unsigned short* __restrict__ V,
                                                  unsigned short* __restrict__ ctx) {
  __shared__ __align__(16) unsigned short Kt[64 * 64];   // [kv][d]
  __shared__ __align__(16) unsigned short Vt[64 * 64];   // [d][kv] (transposed)
  __shared__ __align__(16) unsigned short Pl[4][16 * 64];  // per-wave P [16 q][64 kv]
  const int tid = threadIdx.x;
  const int wid = tid >> 6;
  const int lr = tid & 15;
  const int lk = (tid >> 4) & 3;
  const int qb = blockIdx.x;
  const int bh = blockIdx.y;
  const unsigned short* Qh = Q + (size_t)bh * T_ * D_;
  const unsigned short* Kh = K + (size_t)bh * T_ * D_;
  const unsigned short* Vh = V + (size_t)bh * T_ * D_;
  const int qrow = qb * 64 + wid * 16;  // wave's first q row

  short8 qf[2];
#pragma unroll
  for (int kb = 0; kb < 2; ++kb)
    qf[kb] = *(const short8*)&Qh[(size_t)(qrow + lr) * D_ + kb * 32 + lk * 8];

  f32x4 o[4] = {};
  float mrun[4], lrun[4];
#pragma unroll
  for (int r = 0; r < 4; ++r) { mrun[r] = -1e30f; lrun[r] = 0.f; }

  for (int kvt = 0; kvt <= qb; ++kvt) {
    __syncthreads();  // prior iteration's reads done before restaging
    // stage K tile [64][64] via global_load_lds
#pragma unroll
    for (int pass = 0; pass < 2; ++pass) {
      int chunk = pass * 256 + tid;
      const unsigned short* g = Kh + ((size_t)kvt * 64 + (chunk >> 3)) * D_ + (chunk & 7) * 8;
      unsigned short* l = Kt + (size_t)(pass * 256 + wid * 64) * 8;
      GLOAD_LDS16(g, l);
    }
    // stage V tile transposed (reg-staged)
#pragma unroll
    for (int pass = 0; pass < 2; ++pass) {
      int chunk = pass * 256 + tid;
      int kv = chunk >> 3, d0 = (chunk & 7) * 8;
      short8 v = *(const short8*)&Vh[((size_t)kvt * 64 + kv) * D_ + d0];
#pragma unroll
      for (int j = 0; j < 8; ++j) Vt[(d0 + j) * 64 + kv] = (unsigned short)v[j];
    }
    __syncthreads();

    // S = Q K^T  (16 q-rows x 64 kv)
    f32x4 s[4];
#pragma unroll
    for (int n = 0; n < 4; ++n) {
      f32x4 sn = {0.f, 0.f, 0.f, 0.f};
#pragma unroll
      for (int kb = 0; kb < 2; ++kb) {
        short8 kf = *(const short8*)&Kt[(n * 16 + lr) * 64 + kb * 32 + lk * 8];
        sn = MFMA_BF16(qf[kb], kf, sn);
      }
      s[n] = sn;
    }
    const bool diag = (kvt == qb);
#pragma unroll
    for (int n = 0; n < 4; ++n)
#pragma unroll
      for (int r = 0; r < 4; ++r) {
        float v = s[n][r] * 0.125f;  // 1/sqrt(D)
        if (diag && (n * 16 + lr) > (wid * 16 + lk * 4 + r)) v = -1e30f;
        s[n][r] = v;
      }

    // online softmax: each lane owns rows lk*4+r; row lives in 16 lanes (lr)
#pragma unroll
    for (int r = 0; r < 4; ++r) {
      float mx = fmaxf(fmaxf(s[0][r], s[1][r]), fmaxf(s[2][r], s[3][r]));
      mx = fmaxf(mx, __shfl_xor(mx, 1));
      mx = fmaxf(mx, __shfl_xor(mx, 2));
      mx = fmaxf(mx, __shfl_xor(mx, 4));
      mx = fmaxf(mx, __shfl_xor(mx, 8));
      float mnew = fmaxf(mrun[r], mx);
      float sc = expf(mrun[r] - mnew);
      float rs = 0.f;
#pragma unroll
      for (int n = 0; n < 4; ++n) {
        float p = expf(s[n][r] - mnew);
        s[n][r] = p;
        rs += p;
      }
      rs += __shfl_xor(rs, 1);
      rs += __shfl_xor(rs, 2);
      rs += __shfl_xor(rs, 4);
      rs += __shfl_xor(rs, 8);
      lrun[r] = lrun[r] * sc + rs;
      mrun[r] = mnew;
#pragma unroll
      for (int nd = 0; nd < 4; ++nd) o[nd][r] *= sc;
    }

    // P -> LDS (bf16), per-wave private region; same-wave dep handled by lgkmcnt
#pragma unroll
    for (int n = 0; n < 4; ++n)
#pragma unroll
      for (int r = 0; r < 4; ++r)
        Pl[wid][(lk * 4 + r) * 64 + n * 16 + lr] = f2bf(s[n][r]);

    // O += P V
#pragma unroll
    for (int kb = 0; kb < 2; ++kb) {
      short8 pf = *(const short8*)&Pl[wid][lr * 64 + kb * 32 + lk * 8];
#pragma unroll
      for (int nd = 0; nd < 4; ++nd) {
        short8 vf = *(const short8*)&Vt[(nd * 16 + lr) * 64 + kb * 32 + lk * 8];
        o[nd] = MFMA_BF16(pf, vf, o[nd]);
      }
    }
  }

  const int b = bh >> 4, h = bh & 15;
#pragma unroll
  for (int nd = 0; nd < 4; ++nd)
#pragma unroll
    for (int r = 0; r < 4; ++r) {
      int t = qrow + lk * 4 + r;
      float v = o[nd][r] / lrun[r];
      ctx[((size_t)b * T_ + t) * E_ + h * D_ + nd * 16 + lr] = f2bf(v);
    }
}

// ---------------- launcher ----------------
extern "C" void kernel_launch(void* const* d_in, const int* in_sizes, int n_in,
                              void* d_out, int out_size, void* d_ws, size_t ws_size,
                              hipStream_t stream) {
  const float* x    = (const float*)d_in[0];
  const float* Wq   = (const float*)d_in[1];
  const float* Wk   = (const float*)d_in[2];
  const float* Wv   = (const float*)d_in[3];
  const float* Wout = (const float*)d_in[4];
  const float* bout = (const float*)d_in[5];
  float* out = (float*)d_out;

  const size_t MT = (size_t)B_ * T_;      // 8192
  const size_t XE = MT * E_;              // 8,388,608
  const size_t WE = (size_t)E_ * E_;      // 1,048,576

  // workspace layout (shorts): xb | wq | wk | wv | wo | Q | K | V | ctx
  size_t need = (XE * 5 + WE * 4) * sizeof(unsigned short);
  if (ws_size < need) return;  // clean failure signal

  unsigned short* xb  = (unsigned short*)d_ws;
  unsigned short* wqb = xb + XE;
  unsigned short* wkb = wqb + WE;
  unsigned short* wvb = wkb + WE;
  unsigned short* wob = wvb + WE;
  unsigned short* Qb  = wob + WE;
  unsigned short* Kb  = Qb + XE;
  unsigned short* Vb  = Kb + XE;
  unsigned short* ctx = Vb + XE;

  cvt_f32_bf16<<<(int)(XE / 8 / 256), 256, 0, stream>>>(x, xb, (int)(XE / 8));
  cvt_f32_bf16<<<(int)(WE / 8 / 256), 256, 0, stream>>>(Wq, wqb, (int)(WE / 8));
  cvt_f32_bf16<<<(int)(WE / 8 / 256), 256, 0, stream>>>(Wk, wkb, (int)(WE / 8));
  cvt_f32_bf16<<<(int)(WE / 8 / 256), 256, 0, stream>>>(Wv, wvb, (int)(WE / 8));
  cvt_f32_bf16<<<(int)(WE / 8 / 256), 256, 0, stream>>>(Wout, wob, (int)(WE / 8));

  dim3 ggrid(MT / 128, E_ / 128);  // (64, 8)
  gemm_bt<0><<<ggrid, 256, 0, stream>>>(xb, wqb, Qb, nullptr, (int)MT, E_, E_);
  gemm_bt<0><<<ggrid, 256, 0, stream>>>(xb, wkb, Kb, nullptr, (int)MT, E_, E_);
  gemm_bt<0><<<ggrid, 256, 0, stream>>>(xb, wvb, Vb, nullptr, (int)MT, E_, E_);

  attn_fused<<<dim3(T_ / 64, B_ * H_), 256, 0, stream>>>(Qb, Kb, Vb, ctx);

  gemm_bt<1><<<ggrid, 256, 0, stream>>>(ctx, wob, out, bout, (int)MT, E_, E_);
}

// Round 2
// 369.936 us; speedup vs baseline: 1.4549x; 1.4549x over previous
//
#include <hip/hip_runtime.h>
#include <hip/hip_bf16.h>
#include <stdint.h>
#include <math.h>

#define B_ 4
#define T_ 2048
#define E_ 1024
#define H_ 16
#define D_ 64

typedef __attribute__((ext_vector_type(8))) short short8;
typedef __attribute__((ext_vector_type(4))) float f32x4;

#define MFMA_BF16(a, b, c) __builtin_amdgcn_mfma_f32_16x16x32_bf16((a), (b), (c), 0, 0, 0)

__device__ __forceinline__ unsigned short f2bf(float f) {
  union { float f; unsigned u; } v; v.f = f;
  unsigned r = v.u + 0x7FFFu + ((v.u >> 16) & 1u);  // RNE
  return (unsigned short)(r >> 16);
}

#define GLOAD_LDS16(g, l)                                                        \
  __builtin_amdgcn_global_load_lds((const __attribute__((address_space(1))) void*)(g), \
                                   (__attribute__((address_space(3))) void*)(l), 16, 0, 0)

// ---------------- fp32 -> bf16 convert (vectorized) ----------------
__global__ __launch_bounds__(256) void cvt_f32_bf16(const float* __restrict__ in,
                                                    unsigned short* __restrict__ out,
                                                    int n8) {
  int i = blockIdx.x * blockDim.x + threadIdx.x;
  if (i >= n8) return;
  const float4* p = (const float4*)(in + (size_t)i * 8);
  float4 a = p[0], b = p[1];
  short8 r;
  r[0] = (short)f2bf(a.x); r[1] = (short)f2bf(a.y);
  r[2] = (short)f2bf(a.z); r[3] = (short)f2bf(a.w);
  r[4] = (short)f2bf(b.x); r[5] = (short)f2bf(b.y);
  r[6] = (short)f2bf(b.z); r[7] = (short)f2bf(b.w);
  *(short8*)(out + (size_t)i * 8) = r;
}

// ---------------- GEMM: C[M,N] = A[M,K] * B[N,K]^T (bf16 in, MODE-dep out) ----
// MODE 0: write bf16 to [B,H,T,D] (row m = b*T+t, col n = h*D+d)
// MODE 1: write fp32 row-major [M,N] + bias[n]
template <int MODE>
__global__ __launch_bounds__(256) void gemm_bt(const unsigned short* __restrict__ A,
                                               const unsigned short* __restrict__ Bm,
                                               void* __restrict__ outp,
                                               const float* __restrict__ bias,
                                               int M, int N, int K) {
  __shared__ __align__(16) unsigned short Ab[128 * 64];
  __shared__ __align__(16) unsigned short Bb[128 * 64];
  const int tid = threadIdx.x;
  const int wid = tid >> 6;
  const int lr = tid & 15;        // lane & 15
  const int lk = (tid >> 4) & 3;  // lane >> 4
  const int wr = wid >> 1, wc = wid & 1;
  const int m0 = blockIdx.x * 128, n0 = blockIdx.y * 128;

  f32x4 acc[4][4] = {};

  for (int k0 = 0; k0 < K; k0 += 64) {
    __syncthreads();
#pragma unroll
    for (int pass = 0; pass < 4; ++pass) {
      int chunk = pass * 256 + tid;
      int row = chunk >> 3, inner = chunk & 7;
      const unsigned short* ga = A + (size_t)(m0 + row) * K + k0 + inner * 8;
      const unsigned short* gb = Bm + (size_t)(n0 + row) * K + k0 + inner * 8;
      unsigned short* la = Ab + (size_t)(pass * 256 + wid * 64) * 8;  // wave-uniform base
      unsigned short* lb = Bb + (size_t)(pass * 256 + wid * 64) * 8;
      GLOAD_LDS16(ga, la);
      GLOAD_LDS16(gb, lb);
    }
    __syncthreads();
#pragma unroll
    for (int kk = 0; kk < 2; ++kk) {
      short8 af[4], bf[4];
#pragma unroll
      for (int mi = 0; mi < 4; ++mi)
        af[mi] = *(const short8*)&Ab[(wr * 64 + mi * 16 + lr) * 64 + kk * 32 + lk * 8];
#pragma unroll
      for (int ni = 0; ni < 4; ++ni)
        bf[ni] = *(const short8*)&Bb[(wc * 64 + ni * 16 + lr) * 64 + kk * 32 + lk * 8];
#pragma unroll
      for (int mi = 0; mi < 4; ++mi)
#pragma unroll
        for (int ni = 0; ni < 4; ++ni)
          acc[mi][ni] = MFMA_BF16(af[mi], bf[ni], acc[mi][ni]);
    }
  }

#pragma unroll
  for (int mi = 0; mi < 4; ++mi) {
#pragma unroll
    for (int ni = 0; ni < 4; ++ni) {
#pragma unroll
      for (int r = 0; r < 4; ++r) {
        int row = m0 + wr * 64 + mi * 16 + lk * 4 + r;
        int col = n0 + wc * 64 + ni * 16 + lr;
        float v = acc[mi][ni][r];
        if (MODE == 0) {
          int b = row >> 11, t = row & (T_ - 1), h = col >> 6, d = col & (D_ - 1);
          ((unsigned short*)outp)[(((size_t)(b * H_ + h)) * T_ + t) * D_ + d] = f2bf(v);
        } else {
          ((float*)outp)[(size_t)row * N + col] = v + bias[col];
        }
      }
    }
  }
}

// ---------------- V transpose: [BH][T][D] -> [BH][D][T] ----------------
__global__ __launch_bounds__(256) void transpose_v(const unsigned short* __restrict__ V,
                                                   unsigned short* __restrict__ VT) {
  const int lane = threadIdx.x & 63;
  const int w = threadIdx.x >> 6;
  const int tb = blockIdx.x * 64;
  const int bh = blockIdx.y;
  const unsigned short* Vh = V + (size_t)bh * T_ * D_;
  unsigned short* Vo = VT + (size_t)bh * T_ * D_;
  short8 v0, v1;
#pragma unroll
  for (int j = 0; j < 8; ++j)
    v0[j] = (short)Vh[(size_t)(tb + w * 16 + j) * D_ + lane];
#pragma unroll
  for (int j = 0; j < 8; ++j)
    v1[j] = (short)Vh[(size_t)(tb + w * 16 + 8 + j) * D_ + lane];
  *(short8*)&Vo[(size_t)lane * T_ + tb + w * 16] = v0;
  *(short8*)&Vo[(size_t)lane * T_ + tb + w * 16 + 8] = v1;
}

// ---------------- fused causal flash attention (no staging, no barriers) -----
// Q,K bf16 [B*H,T,D]; VT bf16 [B*H,D,T]; ctx bf16 [B*T,E] (col = h*D+d).
// 1024 blocks x 256 thr; 4 independent waves/block, 32 q-rows per wave.
__global__ __launch_bounds__(256) void attn_fused(const unsigned short* __restrict__ Q,
                                                  const unsigned short* __restrict__ K,
                                                  const unsigned short* __restrict__ VT,
                                                  unsigned short* __restrict__ ctx) {
  __shared__ __align__(16) unsigned short Pl[4][32 * 72];  // per-wave P, stride 72
  const int tid = threadIdx.x;
  const int wid = tid >> 6;
  const int lr = tid & 15;
  const int lk = (tid >> 4) & 3;

  // XCD swizzle: blocks of one head (16) stay on one XCD; heavy q-blocks first.
  const int bid = blockIdx.x;
  const int n_ = (bid & 7) * 128 + (bid >> 3);
  const int bh = n_ >> 4;
  const int qblk = 15 - (n_ & 15);
  const int q0 = qblk * 128 + wid * 32;

  const unsigned short* Qh = Q + (size_t)bh * T_ * D_;
  const unsigned short* Kh = K + (size_t)bh * T_ * D_;
  const unsigned short* Vh = VT + (size_t)bh * T_ * D_;  // [D][T]

  const float SC = 0.125f * 1.44269504089f;  // 1/sqrt(D) * log2(e)

  short8 qf[2][2];
#pragma unroll
  for (int a = 0; a < 2; ++a)
#pragma unroll
    for (int kb = 0; kb < 2; ++kb)
      qf[a][kb] = *(const short8*)&Qh[(size_t)(q0 + a * 16 + lr) * D_ + kb * 32 + lk * 8];

  f32x4 o[2][4] = {};
  float mrun[2][4], lrun[2][4];
#pragma unroll
  for (int a = 0; a < 2; ++a)
#pragma unroll
    for (int r = 0; r < 4; ++r) { mrun[a][r] = -1e30f; lrun[a][r] = 0.f; }

  const int nt = (q0 >> 6) + 1;
  const int rowl0 = (q0 & 63) + lk * 4;  // tile-local row base for a=0

  for (int kvt = 0; kvt < nt; ++kvt) {
    const unsigned short* Kt = Kh + (size_t)kvt * 64 * D_;
    const unsigned short* Vtt = Vh + (size_t)kvt * 64;

    // S = Q K^T  (32 q-rows x 64 kv), streamed from L2
    f32x4 s[2][4] = {};
#pragma unroll
    for (int kb = 0; kb < 2; ++kb) {
      short8 kf[4];
#pragma unroll
      for (int n = 0; n < 4; ++n)
        kf[n] = *(const short8*)&Kt[(size_t)(n * 16 + lr) * D_ + kb * 32 + lk * 8];
#pragma unroll
      for (int a = 0; a < 2; ++a)
#pragma unroll
        for (int n = 0; n < 4; ++n)
          s[a][n] = MFMA_BF16(qf[a][kb], kf[n], s[a][n]);
    }

    if (kvt == nt - 1) {  // diagonal tile: causal mask (raw-domain -inf)
#pragma unroll
      for (int a = 0; a < 2; ++a)
#pragma unroll
        for (int n = 0; n < 4; ++n)
#pragma unroll
          for (int r = 0; r < 4; ++r)
            if (n * 16 + lr > rowl0 + a * 16 + r) s[a][n][r] = -3e38f;
    }

    // online softmax (exp2 domain; scale folded into fma)
#pragma unroll
    for (int a = 0; a < 2; ++a)
#pragma unroll
      for (int r = 0; r < 4; ++r) {
        float mx = fmaxf(fmaxf(s[a][0][r], s[a][1][r]), fmaxf(s[a][2][r], s[a][3][r]));
        mx = fmaxf(mx, __shfl_xor(mx, 1));
        mx = fmaxf(mx, __shfl_xor(mx, 2));
        mx = fmaxf(mx, __shfl_xor(mx, 4));
        mx = fmaxf(mx, __shfl_xor(mx, 8));
        float mnew = fmaxf(mrun[a][r], mx * SC);
        float sc = exp2f(mrun[a][r] - mnew);
        float rs = 0.f;
#pragma unroll
        for (int n = 0; n < 4; ++n) {
          float p = exp2f(fmaf(s[a][n][r], SC, -mnew));
          s[a][n][r] = p;
          rs += p;
        }
        rs += __shfl_xor(rs, 1);
        rs += __shfl_xor(rs, 2);
        rs += __shfl_xor(rs, 4);
        rs += __shfl_xor(rs, 8);
        lrun[a][r] = lrun[a][r] * sc + rs;
        mrun[a][r] = mnew;
#pragma unroll
        for (int nd = 0; nd < 4; ++nd) o[a][nd][r] *= sc;
      }

    // P -> per-wave LDS (bf16), stride 72 to spread banks
    asm volatile("s_waitcnt lgkmcnt(0)" ::: "memory");
#pragma unroll
    for (int a = 0; a < 2; ++a)
#pragma unroll
      for (int n = 0; n < 4; ++n)
#pragma unroll
        for (int r = 0; r < 4; ++r)
          Pl[wid][(a * 16 + lk * 4 + r) * 72 + n * 16 + lr] = f2bf(s[a][n][r]);
    asm volatile("s_waitcnt lgkmcnt(0)" ::: "memory");
    __builtin_amdgcn_sched_barrier(0);

    // O += P V  (V^T rows streamed from L2)
#pragma unroll
    for (int kb = 0; kb < 2; ++kb) {
      short8 pf0 = *(const short8*)&Pl[wid][(lr) * 72 + kb * 32 + lk * 8];
      short8 pf1 = *(const short8*)&Pl[wid][(16 + lr) * 72 + kb * 32 + lk * 8];
#pragma unroll
      for (int nd = 0; nd < 4; ++nd) {
        short8 vf = *(const short8*)&Vtt[(size_t)(nd * 16 + lr) * T_ + kb * 32 + lk * 8];
        o[0][nd] = MFMA_BF16(pf0, vf, o[0][nd]);
        o[1][nd] = MFMA_BF16(pf1, vf, o[1][nd]);
      }
    }
  }

  const int b = bh >> 4, h = bh & 15;
#pragma unroll
  for (int a = 0; a < 2; ++a)
#pragma unroll
    for (int r = 0; r < 4; ++r) {
      float inv = 1.0f / lrun[a][r];
      int t = q0 + a * 16 + lk * 4 + r;
#pragma unroll
      for (int nd = 0; nd < 4; ++nd)
        ctx[((size_t)b * T_ + t) * E_ + h * D_ + nd * 16 + lr] = f2bf(o[a][nd][r] * inv);
    }
}

// ---------------- launcher ----------------
extern "C" void kernel_launch(void* const* d_in, const int* in_sizes, int n_in,
                              void* d_out, int out_size, void* d_ws, size_t ws_size,
                              hipStream_t stream) {
  const float* x    = (const float*)d_in[0];
  const float* Wq   = (const float*)d_in[1];
  const float* Wk   = (const float*)d_in[2];
  const float* Wv   = (const float*)d_in[3];
  const float* Wout = (const float*)d_in[4];
  const float* bout = (const float*)d_in[5];
  float* out = (float*)d_out;

  const size_t MT = (size_t)B_ * T_;      // 8192
  const size_t XE = MT * E_;              // 8,388,608
  const size_t WE = (size_t)E_ * E_;      // 1,048,576

  // workspace layout (shorts): xb | wq | wk | wv | wo | Q | K | VT | ctx
  // (V is materialized into ctx, transposed into VT, then ctx is reused)
  size_t need = (XE * 5 + WE * 4) * sizeof(unsigned short);
  if (ws_size < need) return;  // clean failure signal

  unsigned short* xb  = (unsigned short*)d_ws;
  unsigned short* wqb = xb + XE;
  unsigned short* wkb = wqb + WE;
  unsigned short* wvb = wkb + WE;
  unsigned short* wob = wvb + WE;
  unsigned short* Qb  = wob + WE;
  unsigned short* Kb  = Qb + XE;
  unsigned short* VTb = Kb + XE;
  unsigned short* ctx = VTb + XE;

  cvt_f32_bf16<<<(int)(XE / 8 / 256), 256, 0, stream>>>(x, xb, (int)(XE / 8));
  cvt_f32_bf16<<<(int)(WE / 8 / 256), 256, 0, stream>>>(Wq, wqb, (int)(WE / 8));
  cvt_f32_bf16<<<(int)(WE / 8 / 256), 256, 0, stream>>>(Wk, wkb, (int)(WE / 8));
  cvt_f32_bf16<<<(int)(WE / 8 / 256), 256, 0, stream>>>(Wv, wvb, (int)(WE / 8));
  cvt_f32_bf16<<<(int)(WE / 8 / 256), 256, 0, stream>>>(Wout, wob, (int)(WE / 8));

  dim3 ggrid(MT / 128, E_ / 128);  // (64, 8)
  gemm_bt<0><<<ggrid, 256, 0, stream>>>(xb, wqb, Qb, nullptr, (int)MT, E_, E_);
  gemm_bt<0><<<ggrid, 256, 0, stream>>>(xb, wkb, Kb, nullptr, (int)MT, E_, E_);
  gemm_bt<0><<<ggrid, 256, 0, stream>>>(xb, wvb, ctx, nullptr, (int)MT, E_, E_);  // V -> ctx (temp)

  transpose_v<<<dim3(T_ / 64, B_ * H_), 256, 0, stream>>>(ctx, VTb);

  attn_fused<<<1024, 256, 0, stream>>>(Qb, Kb, VTb, ctx);

  gemm_bt<1><<<ggrid, 256, 0, stream>>>(ctx, wob, out, bout, (int)MT, E_, E_);
}

// Round 3
// 274.819 us; speedup vs baseline: 1.9585x; 1.3461x over previous
//
#include <hip/hip_runtime.h>
#include <hip/hip_bf16.h>
#include <stdint.h>
#include <math.h>

#define B_ 4
#define T_ 2048
#define E_ 1024
#define H_ 16
#define D_ 64

typedef __attribute__((ext_vector_type(8))) short short8;
typedef __attribute__((ext_vector_type(4))) float f32x4;

#define MFMA_BF16(a, b, c) __builtin_amdgcn_mfma_f32_16x16x32_bf16((a), (b), (c), 0, 0, 0)

__device__ __forceinline__ unsigned short f2bf(float f) {
  union { float f; unsigned u; } v; v.f = f;
  unsigned r = v.u + 0x7FFFu + ((v.u >> 16) & 1u);  // RNE
  return (unsigned short)(r >> 16);
}

#define GLOAD_LDS16(g, l)                                                        \
  __builtin_amdgcn_global_load_lds((const __attribute__((address_space(1))) void*)(g), \
                                   (__attribute__((address_space(3))) void*)(l), 16, 0, 0)

// ---------------- fp32 -> bf16 convert (vectorized) ----------------
__global__ __launch_bounds__(256) void cvt_f32_bf16(const float* __restrict__ in,
                                                    unsigned short* __restrict__ out,
                                                    int n8) {
  int i = blockIdx.x * blockDim.x + threadIdx.x;
  if (i >= n8) return;
  const float4* p = (const float4*)(in + (size_t)i * 8);
  float4 a = p[0], b = p[1];
  short8 r;
  r[0] = (short)f2bf(a.x); r[1] = (short)f2bf(a.y);
  r[2] = (short)f2bf(a.z); r[3] = (short)f2bf(a.w);
  r[4] = (short)f2bf(b.x); r[5] = (short)f2bf(b.y);
  r[6] = (short)f2bf(b.z); r[7] = (short)f2bf(b.w);
  *(short8*)(out + (size_t)i * 8) = r;
}

// 4 weight matrices in one launch (dest regions contiguous in ws)
__global__ __launch_bounds__(256) void cvt_w4(const float* __restrict__ w0,
                                              const float* __restrict__ w1,
                                              const float* __restrict__ w2,
                                              const float* __restrict__ w3,
                                              unsigned short* __restrict__ out) {
  int i = blockIdx.x * blockDim.x + threadIdx.x;  // one per 8 elems
  int which = i >> 17;                            // WE/8 = 2^17
  int off = i & 131071;
  const float* src = (which == 0) ? w0 : (which == 1) ? w1 : (which == 2) ? w2 : w3;
  const float4* p = (const float4*)(src + (size_t)off * 8);
  float4 a = p[0], b = p[1];
  short8 r;
  r[0] = (short)f2bf(a.x); r[1] = (short)f2bf(a.y);
  r[2] = (short)f2bf(a.z); r[3] = (short)f2bf(a.w);
  r[4] = (short)f2bf(b.x); r[5] = (short)f2bf(b.y);
  r[6] = (short)f2bf(b.z); r[7] = (short)f2bf(b.w);
  *(short8*)(out + ((size_t)which << 20) + (size_t)off * 8) = r;
}

// ---------------- fused QKV GEMM: C = x * W^T for W in {Wq,Wk,Wv} -------------
// grid (64, 24): by selects matrix (by>>3) and n-panel ((by&7)*128).
// Output bf16 [B,H,T,D] per matrix.
__global__ __launch_bounds__(256) void gemm_qkv(const unsigned short* __restrict__ A,
                                                const unsigned short* __restrict__ Wq,
                                                const unsigned short* __restrict__ Wk,
                                                const unsigned short* __restrict__ Wv,
                                                unsigned short* __restrict__ Qo,
                                                unsigned short* __restrict__ Ko,
                                                unsigned short* __restrict__ Vo) {
  __shared__ __align__(16) unsigned short Ab[128 * 64];
  __shared__ __align__(16) unsigned short Bb[128 * 64];
  const int K = E_;
  const int tid = threadIdx.x;
  const int wid = tid >> 6;
  const int lr = tid & 15;
  const int lk = (tid >> 4) & 3;
  const int wr = wid >> 1, wc = wid & 1;
  const int m0 = blockIdx.x * 128;
  const int sel = blockIdx.y >> 3;
  const int n0 = (blockIdx.y & 7) * 128;
  const unsigned short* Bm = (sel == 0) ? Wq : (sel == 1) ? Wk : Wv;
  unsigned short* outp = (sel == 0) ? Qo : (sel == 1) ? Ko : Vo;

  f32x4 acc[4][4] = {};

  for (int k0 = 0; k0 < K; k0 += 64) {
    __syncthreads();
#pragma unroll
    for (int pass = 0; pass < 4; ++pass) {
      int chunk = pass * 256 + tid;
      int row = chunk >> 3, inner = chunk & 7;
      const unsigned short* ga = A + (size_t)(m0 + row) * K + k0 + inner * 8;
      const unsigned short* gb = Bm + (size_t)(n0 + row) * K + k0 + inner * 8;
      unsigned short* la = Ab + (size_t)(pass * 256 + wid * 64) * 8;
      unsigned short* lb = Bb + (size_t)(pass * 256 + wid * 64) * 8;
      GLOAD_LDS16(ga, la);
      GLOAD_LDS16(gb, lb);
    }
    __syncthreads();
#pragma unroll
    for (int kk = 0; kk < 2; ++kk) {
      short8 af[4], bf[4];
#pragma unroll
      for (int mi = 0; mi < 4; ++mi)
        af[mi] = *(const short8*)&Ab[(wr * 64 + mi * 16 + lr) * 64 + kk * 32 + lk * 8];
#pragma unroll
      for (int ni = 0; ni < 4; ++ni)
        bf[ni] = *(const short8*)&Bb[(wc * 64 + ni * 16 + lr) * 64 + kk * 32 + lk * 8];
#pragma unroll
      for (int mi = 0; mi < 4; ++mi)
#pragma unroll
        for (int ni = 0; ni < 4; ++ni)
          acc[mi][ni] = MFMA_BF16(af[mi], bf[ni], acc[mi][ni]);
    }
  }

#pragma unroll
  for (int mi = 0; mi < 4; ++mi)
#pragma unroll
    for (int ni = 0; ni < 4; ++ni)
#pragma unroll
      for (int r = 0; r < 4; ++r) {
        int row = m0 + wr * 64 + mi * 16 + lk * 4 + r;
        int col = n0 + wc * 64 + ni * 16 + lr;
        int b = row >> 11, t = row & (T_ - 1), h = col >> 6, d = col & (D_ - 1);
        outp[(((size_t)(b * H_ + h)) * T_ + t) * D_ + d] = f2bf(acc[mi][ni][r]);
      }
}

// ---------------- out-proj GEMM: fp32 out + bias ----------------
__global__ __launch_bounds__(256) void gemm_out(const unsigned short* __restrict__ A,
                                                const unsigned short* __restrict__ Bm,
                                                float* __restrict__ outp,
                                                const float* __restrict__ bias,
                                                int M, int N, int K) {
  __shared__ __align__(16) unsigned short Ab[128 * 64];
  __shared__ __align__(16) unsigned short Bb[128 * 64];
  const int tid = threadIdx.x;
  const int wid = tid >> 6;
  const int lr = tid & 15;
  const int lk = (tid >> 4) & 3;
  const int wr = wid >> 1, wc = wid & 1;
  const int m0 = blockIdx.x * 128, n0 = blockIdx.y * 128;

  f32x4 acc[4][4] = {};

  for (int k0 = 0; k0 < K; k0 += 64) {
    __syncthreads();
#pragma unroll
    for (int pass = 0; pass < 4; ++pass) {
      int chunk = pass * 256 + tid;
      int row = chunk >> 3, inner = chunk & 7;
      const unsigned short* ga = A + (size_t)(m0 + row) * K + k0 + inner * 8;
      const unsigned short* gb = Bm + (size_t)(n0 + row) * K + k0 + inner * 8;
      unsigned short* la = Ab + (size_t)(pass * 256 + wid * 64) * 8;
      unsigned short* lb = Bb + (size_t)(pass * 256 + wid * 64) * 8;
      GLOAD_LDS16(ga, la);
      GLOAD_LDS16(gb, lb);
    }
    __syncthreads();
#pragma unroll
    for (int kk = 0; kk < 2; ++kk) {
      short8 af[4], bf[4];
#pragma unroll
      for (int mi = 0; mi < 4; ++mi)
        af[mi] = *(const short8*)&Ab[(wr * 64 + mi * 16 + lr) * 64 + kk * 32 + lk * 8];
#pragma unroll
      for (int ni = 0; ni < 4; ++ni)
        bf[ni] = *(const short8*)&Bb[(wc * 64 + ni * 16 + lr) * 64 + kk * 32 + lk * 8];
#pragma unroll
      for (int mi = 0; mi < 4; ++mi)
#pragma unroll
        for (int ni = 0; ni < 4; ++ni)
          acc[mi][ni] = MFMA_BF16(af[mi], bf[ni], acc[mi][ni]);
    }
  }

#pragma unroll
  for (int mi = 0; mi < 4; ++mi)
#pragma unroll
    for (int ni = 0; ni < 4; ++ni)
#pragma unroll
      for (int r = 0; r < 4; ++r) {
        int row = m0 + wr * 64 + mi * 16 + lk * 4 + r;
        int col = n0 + wc * 64 + ni * 16 + lr;
        outp[(size_t)row * N + col] = acc[mi][ni][r] + bias[col];
      }
}

// ---------------- V transpose: [BH][T][D] -> [BH][D][T] ----------------
__global__ __launch_bounds__(256) void transpose_v(const unsigned short* __restrict__ V,
                                                   unsigned short* __restrict__ VT) {
  const int lane = threadIdx.x & 63;
  const int w = threadIdx.x >> 6;
  const int tb = blockIdx.x * 64;
  const int bh = blockIdx.y;
  const unsigned short* Vh = V + (size_t)bh * T_ * D_;
  unsigned short* Vo = VT + (size_t)bh * T_ * D_;
  short8 v0, v1;
#pragma unroll
  for (int j = 0; j < 8; ++j)
    v0[j] = (short)Vh[(size_t)(tb + w * 16 + j) * D_ + lane];
#pragma unroll
  for (int j = 0; j < 8; ++j)
    v1[j] = (short)Vh[(size_t)(tb + w * 16 + 8 + j) * D_ + lane];
  *(short8*)&Vo[(size_t)lane * T_ + tb + w * 16] = v0;
  *(short8*)&Vo[(size_t)lane * T_ + tb + w * 16 + 8] = v1;
}

// ---------------- fused causal flash attention ----------------
// One wave per block; 4096 blocks = 64 heads x 64 q-chunks of 32 rows.
// Q,K bf16 [B*H,T,D]; VT bf16 [B*H,D,T]; ctx bf16 [B*T,E].
// No barriers; K/V^T streamed from L2; row-sum via MFMA against ones;
// defer-max (T13) skips O-rescale when max growth <= 8 (exp2 domain).
__global__ __launch_bounds__(64) void attn_fused(const unsigned short* __restrict__ Q,
                                                 const unsigned short* __restrict__ K,
                                                 const unsigned short* __restrict__ VT,
                                                 unsigned short* __restrict__ ctx) {
  __shared__ __align__(16) unsigned short Pl[32 * 72];
  const int tid = threadIdx.x;
  const int lr = tid & 15;
  const int lk = tid >> 4;

  // XCD swizzle: 8 heads per XCD; heaviest q-chunks dispatched first.
  const int bid = blockIdx.x;
  const int xcd = bid & 7;
  const int n_ = bid >> 3;           // 0..511 per XCD
  const int chunk = 63 - (n_ >> 3);  // heavy first
  const int bh = xcd * 8 + (n_ & 7);
  const int q0 = chunk * 32;

  const unsigned short* Qh = Q + (size_t)bh * T_ * D_;
  const unsigned short* Kh = K + (size_t)bh * T_ * D_;
  const unsigned short* Vh = VT + (size_t)bh * T_ * D_;  // [D][T]

  const float SC = 0.125f * 1.44269504089f;  // 1/sqrt(D) * log2(e)

  short8 vones;
#pragma unroll
  for (int j = 0; j < 8; ++j) vones[j] = (short)0x3F80;  // bf16 1.0

  short8 qf[2][2];
#pragma unroll
  for (int a = 0; a < 2; ++a)
#pragma unroll
    for (int kb = 0; kb < 2; ++kb)
      qf[a][kb] = *(const short8*)&Qh[(size_t)(q0 + a * 16 + lr) * D_ + kb * 32 + lk * 8];

  f32x4 o[2][4] = {};
  f32x4 lsum[2] = {};
  float mrun[2][4];
#pragma unroll
  for (int a = 0; a < 2; ++a)
#pragma unroll
    for (int r = 0; r < 4; ++r) mrun[a][r] = -1e30f;

  const int nt = (q0 >> 6) + 1;
  const int rowl0 = (q0 & 63) + lk * 4;  // tile-local row base (a=0)

  for (int kvt = 0; kvt < nt; ++kvt) {
    const unsigned short* Kt = Kh + (size_t)kvt * 64 * D_;
    const unsigned short* Vtt = Vh + (size_t)kvt * 64;

    // S = Q K^T (32 q-rows x 64 kv)
    f32x4 s[2][4] = {};
#pragma unroll
    for (int kb = 0; kb < 2; ++kb) {
      short8 kf[4];
#pragma unroll
      for (int n = 0; n < 4; ++n)
        kf[n] = *(const short8*)&Kt[(size_t)(n * 16 + lr) * D_ + kb * 32 + lk * 8];
#pragma unroll
      for (int a = 0; a < 2; ++a)
#pragma unroll
        for (int n = 0; n < 4; ++n)
          s[a][n] = MFMA_BF16(qf[a][kb], kf[n], s[a][n]);
    }

    if (kvt == nt - 1) {  // diagonal tile: causal mask
#pragma unroll
      for (int a = 0; a < 2; ++a)
#pragma unroll
        for (int n = 0; n < 4; ++n)
#pragma unroll
          for (int r = 0; r < 4; ++r)
            if (n * 16 + lr > rowl0 + a * 16 + r) s[a][n][r] = -3e38f;
    }

    // row max (16-lane shuffle reduce), exp2 domain
    float pm[2][4];
    float need = -1e30f;
#pragma unroll
    for (int a = 0; a < 2; ++a)
#pragma unroll
      for (int r = 0; r < 4; ++r) {
        float mx = fmaxf(fmaxf(s[a][0][r], s[a][1][r]), fmaxf(s[a][2][r], s[a][3][r]));
        mx = fmaxf(mx, __shfl_xor(mx, 1));
        mx = fmaxf(mx, __shfl_xor(mx, 2));
        mx = fmaxf(mx, __shfl_xor(mx, 4));
        mx = fmaxf(mx, __shfl_xor(mx, 8));
        pm[a][r] = mx * SC;
        need = fmaxf(need, pm[a][r] - mrun[a][r]);
      }

    if (__any(need > 8.f)) {  // rescale (T13 defer-max)
#pragma unroll
      for (int a = 0; a < 2; ++a)
#pragma unroll
        for (int r = 0; r < 4; ++r) {
          float mnew = fmaxf(mrun[a][r], pm[a][r]);
          float sc = exp2f(mrun[a][r] - mnew);
          mrun[a][r] = mnew;
          lsum[a][r] *= sc;
#pragma unroll
          for (int nd = 0; nd < 4; ++nd) o[a][nd][r] *= sc;
        }
    }

    // P = exp2(S*SC - m) -> bf16 -> per-wave LDS
#pragma unroll
    for (int a = 0; a < 2; ++a)
#pragma unroll
      for (int n = 0; n < 4; ++n)
#pragma unroll
        for (int r = 0; r < 4; ++r) {
          float p = exp2f(fmaf(s[a][n][r], SC, -mrun[a][r]));
          __hip_bfloat16 hb = __float2bfloat16(p);
          Pl[(a * 16 + lk * 4 + r) * 72 + n * 16 + lr] = *(unsigned short*)&hb;
        }
    asm volatile("s_waitcnt lgkmcnt(0)" ::: "memory");
    __builtin_amdgcn_sched_barrier(0);

    // O += P V ; lsum += P * ones (row-sums via MFMA)
#pragma unroll
    for (int kb = 0; kb < 2; ++kb) {
      short8 pf0 = *(const short8*)&Pl[(lr) * 72 + kb * 32 + lk * 8];
      short8 pf1 = *(const short8*)&Pl[(16 + lr) * 72 + kb * 32 + lk * 8];
#pragma unroll
      for (int nd = 0; nd < 4; ++nd) {
        short8 vf = *(const short8*)&Vtt[(size_t)(nd * 16 + lr) * T_ + kb * 32 + lk * 8];
        o[0][nd] = MFMA_BF16(pf0, vf, o[0][nd]);
        o[1][nd] = MFMA_BF16(pf1, vf, o[1][nd]);
      }
      lsum[0] = MFMA_BF16(pf0, vones, lsum[0]);
      lsum[1] = MFMA_BF16(pf1, vones, lsum[1]);
    }
  }

  const int b = bh >> 4, h = bh & 15;
#pragma unroll
  for (int a = 0; a < 2; ++a)
#pragma unroll
    for (int r = 0; r < 4; ++r) {
      float inv = 1.0f / lsum[a][r];
      int t = q0 + a * 16 + lk * 4 + r;
#pragma unroll
      for (int nd = 0; nd < 4; ++nd)
        ctx[((size_t)b * T_ + t) * E_ + h * D_ + nd * 16 + lr] = f2bf(o[a][nd][r] * inv);
    }
}

// ---------------- launcher ----------------
extern "C" void kernel_launch(void* const* d_in, const int* in_sizes, int n_in,
                              void* d_out, int out_size, void* d_ws, size_t ws_size,
                              hipStream_t stream) {
  const float* x    = (const float*)d_in[0];
  const float* Wq   = (const float*)d_in[1];
  const float* Wk   = (const float*)d_in[2];
  const float* Wv   = (const float*)d_in[3];
  const float* Wout = (const float*)d_in[4];
  const float* bout = (const float*)d_in[5];
  float* out = (float*)d_out;

  const size_t MT = (size_t)B_ * T_;      // 8192
  const size_t XE = MT * E_;              // 8,388,608
  const size_t WE = (size_t)E_ * E_;      // 1,048,576

  // workspace layout (shorts): xb | wq|wk|wv|wo | Q | K | VT | ctx
  size_t need = (XE * 5 + WE * 4) * sizeof(unsigned short);
  if (ws_size < need) return;

  unsigned short* xb  = (unsigned short*)d_ws;
  unsigned short* wqb = xb + XE;
  unsigned short* wkb = wqb + WE;
  unsigned short* wvb = wkb + WE;
  unsigned short* wob = wvb + WE;
  unsigned short* Qb  = wob + WE;
  unsigned short* Kb  = Qb + XE;
  unsigned short* VTb = Kb + XE;
  unsigned short* ctx = VTb + XE;

  cvt_f32_bf16<<<(int)(XE / 8 / 256), 256, 0, stream>>>(x, xb, (int)(XE / 8));
  cvt_w4<<<2048, 256, 0, stream>>>(Wq, Wk, Wv, Wout, wqb);

  gemm_qkv<<<dim3(MT / 128, 24), 256, 0, stream>>>(xb, wqb, wkb, wvb, Qb, Kb, ctx);

  transpose_v<<<dim3(T_ / 64, B_ * H_), 256, 0, stream>>>(ctx, VTb);

  attn_fused<<<4096, 64, 0, stream>>>(Qb, Kb, VTb, ctx);

  gemm_out<<<dim3(MT / 128, E_ / 128), 256, 0, stream>>>(ctx, wob, out, bout, (int)MT, E_, E_);
}

// Round 4
// 256.040 us; speedup vs baseline: 2.1022x; 1.0733x over previous
//
#include <hip/hip_runtime.h>
#include <hip/hip_bf16.h>
#include <stdint.h>
#include <math.h>

#define B_ 4
#define T_ 2048
#define E_ 1024
#define H_ 16
#define D_ 64

typedef __attribute__((ext_vector_type(8))) short short8;
typedef __attribute__((ext_vector_type(4))) float f32x4;

#define MFMA_BF16(a, b, c) __builtin_amdgcn_mfma_f32_16x16x32_bf16((a), (b), (c), 0, 0, 0)

__device__ __forceinline__ unsigned short f2bf(float f) {
  union { float f; unsigned u; } v; v.f = f;
  unsigned r = v.u + 0x7FFFu + ((v.u >> 16) & 1u);  // RNE
  return (unsigned short)(r >> 16);
}

#define GLOAD_LDS16(g, l)                                                        \
  __builtin_amdgcn_global_load_lds((const __attribute__((address_space(1))) void*)(g), \
                                   (__attribute__((address_space(3))) void*)(l), 16, 0, 0)

// ---------------- fp32 -> bf16 convert (vectorized) ----------------
__global__ __launch_bounds__(256) void cvt_f32_bf16(const float* __restrict__ in,
                                                    unsigned short* __restrict__ out,
                                                    int n8) {
  int i = blockIdx.x * blockDim.x + threadIdx.x;
  if (i >= n8) return;
  const float4* p = (const float4*)(in + (size_t)i * 8);
  float4 a = p[0], b = p[1];
  short8 r;
  r[0] = (short)f2bf(a.x); r[1] = (short)f2bf(a.y);
  r[2] = (short)f2bf(a.z); r[3] = (short)f2bf(a.w);
  r[4] = (short)f2bf(b.x); r[5] = (short)f2bf(b.y);
  r[6] = (short)f2bf(b.z); r[7] = (short)f2bf(b.w);
  *(short8*)(out + (size_t)i * 8) = r;
}

// 4 weight matrices in one launch (dest regions contiguous in ws)
__global__ __launch_bounds__(256) void cvt_w4(const float* __restrict__ w0,
                                              const float* __restrict__ w1,
                                              const float* __restrict__ w2,
                                              const float* __restrict__ w3,
                                              unsigned short* __restrict__ out) {
  int i = blockIdx.x * blockDim.x + threadIdx.x;  // one per 8 elems
  int which = i >> 17;                            // WE/8 = 2^17
  int off = i & 131071;
  const float* src = (which == 0) ? w0 : (which == 1) ? w1 : (which == 2) ? w2 : w3;
  const float4* p = (const float4*)(src + (size_t)off * 8);
  float4 a = p[0], b = p[1];
  short8 r;
  r[0] = (short)f2bf(a.x); r[1] = (short)f2bf(a.y);
  r[2] = (short)f2bf(a.z); r[3] = (short)f2bf(a.w);
  r[4] = (short)f2bf(b.x); r[5] = (short)f2bf(b.y);
  r[6] = (short)f2bf(b.z); r[7] = (short)f2bf(b.w);
  *(short8*)(out + ((size_t)which << 20) + (size_t)off * 8) = r;
}

// ---------------- fused QKV GEMM: C = x * W^T for W in {Wq,Wk,Wv} -------------
__global__ __launch_bounds__(256) void gemm_qkv(const unsigned short* __restrict__ A,
                                                const unsigned short* __restrict__ Wq,
                                                const unsigned short* __restrict__ Wk,
                                                const unsigned short* __restrict__ Wv,
                                                unsigned short* __restrict__ Qo,
                                                unsigned short* __restrict__ Ko,
                                                unsigned short* __restrict__ Vo) {
  __shared__ __align__(16) unsigned short Ab[128 * 64];
  __shared__ __align__(16) unsigned short Bb[128 * 64];
  const int K = E_;
  const int tid = threadIdx.x;
  const int wid = tid >> 6;
  const int lr = tid & 15;
  const int lk = (tid >> 4) & 3;
  const int wr = wid >> 1, wc = wid & 1;
  const int m0 = blockIdx.x * 128;
  const int sel = blockIdx.y >> 3;
  const int n0 = (blockIdx.y & 7) * 128;
  const unsigned short* Bm = (sel == 0) ? Wq : (sel == 1) ? Wk : Wv;
  unsigned short* outp = (sel == 0) ? Qo : (sel == 1) ? Ko : Vo;

  f32x4 acc[4][4] = {};

  for (int k0 = 0; k0 < K; k0 += 64) {
    __syncthreads();
#pragma unroll
    for (int pass = 0; pass < 4; ++pass) {
      int chunk = pass * 256 + tid;
      int row = chunk >> 3, inner = chunk & 7;
      const unsigned short* ga = A + (size_t)(m0 + row) * K + k0 + inner * 8;
      const unsigned short* gb = Bm + (size_t)(n0 + row) * K + k0 + inner * 8;
      unsigned short* la = Ab + (size_t)(pass * 256 + wid * 64) * 8;
      unsigned short* lb = Bb + (size_t)(pass * 256 + wid * 64) * 8;
      GLOAD_LDS16(ga, la);
      GLOAD_LDS16(gb, lb);
    }
    __syncthreads();
#pragma unroll
    for (int kk = 0; kk < 2; ++kk) {
      short8 af[4], bf[4];
#pragma unroll
      for (int mi = 0; mi < 4; ++mi)
        af[mi] = *(const short8*)&Ab[(wr * 64 + mi * 16 + lr) * 64 + kk * 32 + lk * 8];
#pragma unroll
      for (int ni = 0; ni < 4; ++ni)
        bf[ni] = *(const short8*)&Bb[(wc * 64 + ni * 16 + lr) * 64 + kk * 32 + lk * 8];
#pragma unroll
      for (int mi = 0; mi < 4; ++mi)
#pragma unroll
        for (int ni = 0; ni < 4; ++ni)
          acc[mi][ni] = MFMA_BF16(af[mi], bf[ni], acc[mi][ni]);
    }
  }

#pragma unroll
  for (int mi = 0; mi < 4; ++mi)
#pragma unroll
    for (int ni = 0; ni < 4; ++ni)
#pragma unroll
      for (int r = 0; r < 4; ++r) {
        int row = m0 + wr * 64 + mi * 16 + lk * 4 + r;
        int col = n0 + wc * 64 + ni * 16 + lr;
        int b = row >> 11, t = row & (T_ - 1), h = col >> 6, d = col & (D_ - 1);
        outp[(((size_t)(b * H_ + h)) * T_ + t) * D_ + d] = f2bf(acc[mi][ni][r]);
      }
}

// ---------------- out-proj GEMM: fp32 out + bias ----------------
__global__ __launch_bounds__(256) void gemm_out(const unsigned short* __restrict__ A,
                                                const unsigned short* __restrict__ Bm,
                                                float* __restrict__ outp,
                                                const float* __restrict__ bias,
                                                int M, int N, int K) {
  __shared__ __align__(16) unsigned short Ab[128 * 64];
  __shared__ __align__(16) unsigned short Bb[128 * 64];
  const int tid = threadIdx.x;
  const int wid = tid >> 6;
  const int lr = tid & 15;
  const int lk = (tid >> 4) & 3;
  const int wr = wid >> 1, wc = wid & 1;
  const int m0 = blockIdx.x * 128, n0 = blockIdx.y * 128;

  f32x4 acc[4][4] = {};

  for (int k0 = 0; k0 < K; k0 += 64) {
    __syncthreads();
#pragma unroll
    for (int pass = 0; pass < 4; ++pass) {
      int chunk = pass * 256 + tid;
      int row = chunk >> 3, inner = chunk & 7;
      const unsigned short* ga = A + (size_t)(m0 + row) * K + k0 + inner * 8;
      const unsigned short* gb = Bm + (size_t)(n0 + row) * K + k0 + inner * 8;
      unsigned short* la = Ab + (size_t)(pass * 256 + wid * 64) * 8;
      unsigned short* lb = Bb + (size_t)(pass * 256 + wid * 64) * 8;
      GLOAD_LDS16(ga, la);
      GLOAD_LDS16(gb, lb);
    }
    __syncthreads();
#pragma unroll
    for (int kk = 0; kk < 2; ++kk) {
      short8 af[4], bf[4];
#pragma unroll
      for (int mi = 0; mi < 4; ++mi)
        af[mi] = *(const short8*)&Ab[(wr * 64 + mi * 16 + lr) * 64 + kk * 32 + lk * 8];
#pragma unroll
      for (int ni = 0; ni < 4; ++ni)
        bf[ni] = *(const short8*)&Bb[(wc * 64 + ni * 16 + lr) * 64 + kk * 32 + lk * 8];
#pragma unroll
      for (int mi = 0; mi < 4; ++mi)
#pragma unroll
        for (int ni = 0; ni < 4; ++ni)
          acc[mi][ni] = MFMA_BF16(af[mi], bf[ni], acc[mi][ni]);
    }
  }

#pragma unroll
  for (int mi = 0; mi < 4; ++mi)
#pragma unroll
    for (int ni = 0; ni < 4; ++ni)
#pragma unroll
      for (int r = 0; r < 4; ++r) {
        int row = m0 + wr * 64 + mi * 16 + lk * 4 + r;
        int col = n0 + wc * 64 + ni * 16 + lr;
        outp[(size_t)row * N + col] = acc[mi][ni][r] + bias[col];
      }
}

// ---------------- V transpose: [BH][T][D] -> [BH][D][T] ----------------
__global__ __launch_bounds__(256) void transpose_v(const unsigned short* __restrict__ V,
                                                   unsigned short* __restrict__ VT) {
  const int lane = threadIdx.x & 63;
  const int w = threadIdx.x >> 6;
  const int tb = blockIdx.x * 64;
  const int bh = blockIdx.y;
  const unsigned short* Vh = V + (size_t)bh * T_ * D_;
  unsigned short* Vo = VT + (size_t)bh * T_ * D_;
  short8 v0, v1;
#pragma unroll
  for (int j = 0; j < 8; ++j)
    v0[j] = (short)Vh[(size_t)(tb + w * 16 + j) * D_ + lane];
#pragma unroll
  for (int j = 0; j < 8; ++j)
    v1[j] = (short)Vh[(size_t)(tb + w * 16 + 8 + j) * D_ + lane];
  *(short8*)&Vo[(size_t)lane * T_ + tb + w * 16] = v0;
  *(short8*)&Vo[(size_t)lane * T_ + tb + w * 16 + 8] = v1;
}

// ---------------- fused causal flash attention (swapped QK^T) ----------------
// 1024 blocks x 256 thr; 4 waves/block = 4 consecutive 32-row q-chunks of ONE
// head. No barriers. S^T = mfma(K,Q) puts a full q-column per lane: in-lane
// softmax (2 shuffles/row-max), packed b64 P writes into XOR-swizzled LDS,
// ds_read_b128 P fragments, lsum via MFMA-ones, defer-max rescale.
__global__ __launch_bounds__(256) void attn_fused(const unsigned short* __restrict__ Q,
                                                  const unsigned short* __restrict__ K,
                                                  const unsigned short* __restrict__ VT,
                                                  unsigned short* __restrict__ ctx) {
  __shared__ __align__(16) unsigned short Pl[4 * 32 * 72];
  const int tid = threadIdx.x;
  const int wid = tid >> 6;
  const int lane = tid & 63;
  const int lr = lane & 15;
  const int lk = lane >> 4;
  const int sw = (lr & 7) << 4;  // LDS XOR swizzle (bytes)

  // XCD swizzle: 8 heads/XCD; heaviest chunk-groups dispatched first.
  const int bid = blockIdx.x;
  const int xcd = bid & 7;
  const int p = bid >> 3;              // 0..127 per XCD
  const int bh = xcd * 8 + (p & 7);
  const int group = 15 - (p >> 3);     // heavy first
  const int c = group * 4 + wid;       // q-chunk 0..63
  const int q0 = c * 32;

  const unsigned short* Qh = Q + (size_t)bh * T_ * D_;
  const unsigned short* Kh = K + (size_t)bh * T_ * D_;
  const unsigned short* Vh = VT + (size_t)bh * T_ * D_;  // [D][T]
  char* Pb = (char*)Pl + wid * 4608;                     // 32 rows x 144B

  const float SC = 0.125f * 1.44269504089f;  // 1/sqrt(D) * log2(e)

  short8 vones;
#pragma unroll
  for (int j = 0; j < 8; ++j) vones[j] = (short)0x3F80;  // bf16 1.0

  // Q as B-operand: col=q=lr, k=d
  short8 qf[2][2];
#pragma unroll
  for (int a = 0; a < 2; ++a)
#pragma unroll
    for (int kb = 0; kb < 2; ++kb)
      qf[a][kb] = *(const short8*)&Qh[(size_t)(q0 + a * 16 + lr) * D_ + kb * 32 + lk * 8];

  f32x4 o[2][4] = {};
  f32x4 lsum[2] = {};
  float mrun[2] = {-1e30f, -1e30f};

  const int nt = (q0 >> 6) + 1;
  const int ql0 = (q0 & 63);  // q-local base within diag tile

  for (int kvt = 0; kvt < nt; ++kvt) {
    const unsigned short* Kt = Kh + (size_t)kvt * 64 * D_;
    const unsigned short* Vtt = Vh + (size_t)kvt * 64;

    // S^T = K Q^T : row=kv (lk*4+r +16n), col=q (lr)
    f32x4 st[2][4] = {};
#pragma unroll
    for (int kb = 0; kb < 2; ++kb) {
      short8 kf[4];
#pragma unroll
      for (int n = 0; n < 4; ++n)
        kf[n] = *(const short8*)&Kt[(size_t)(n * 16 + lr) * D_ + kb * 32 + lk * 8];
#pragma unroll
      for (int a = 0; a < 2; ++a)
#pragma unroll
        for (int n = 0; n < 4; ++n)
          st[a][n] = MFMA_BF16(kf[n], qf[a][kb], st[a][n]);
    }

    if (kvt == nt - 1) {  // diagonal tile: mask kv_local > q_local
#pragma unroll
      for (int a = 0; a < 2; ++a)
#pragma unroll
        for (int n = 0; n < 4; ++n)
#pragma unroll
          for (int r = 0; r < 4; ++r)
            if (n * 16 + lk * 4 + r > ql0 + a * 16 + lr) st[a][n][r] = -3e38f;
    }

    // row max: 16 in-lane values + 2 shuffles across lk-groups
    float pm[2];
    float need;
#pragma unroll
    for (int a = 0; a < 2; ++a) {
      float mx = st[a][0][0];
#pragma unroll
      for (int n = 0; n < 4; ++n)
#pragma unroll
        for (int r = 0; r < 4; ++r) mx = fmaxf(mx, st[a][n][r]);
      mx = fmaxf(mx, __shfl_xor(mx, 16));
      mx = fmaxf(mx, __shfl_xor(mx, 32));
      pm[a] = mx * SC;
    }
    need = fmaxf(pm[0] - mrun[0], pm[1] - mrun[1]);

    if (__any(need > 8.f)) {  // defer-max rescale (rare)
#pragma unroll
      for (int a = 0; a < 2; ++a) {
        float mnew = fmaxf(mrun[a], pm[a]);
        float sc = exp2f(mrun[a] - mnew);
        mrun[a] = mnew;
#pragma unroll
        for (int r = 0; r < 4; ++r) {
          float sco = __shfl(sc, (lane & 48) | (lk * 4 + r));
          lsum[a][r] *= sco;
#pragma unroll
          for (int nd = 0; nd < 4; ++nd) o[a][nd][r] *= sco;
        }
      }
    }

    // P = exp2(S*SC - m), packed bf16x4 -> swizzled LDS (8x ds_write_b64)
#pragma unroll
    for (int a = 0; a < 2; ++a)
#pragma unroll
      for (int n = 0; n < 4; ++n) {
        float2 p01, p23;
        p01.x = exp2f(fmaf(st[a][n][0], SC, -mrun[a]));
        p01.y = exp2f(fmaf(st[a][n][1], SC, -mrun[a]));
        p23.x = exp2f(fmaf(st[a][n][2], SC, -mrun[a]));
        p23.y = exp2f(fmaf(st[a][n][3], SC, -mrun[a]));
        __hip_bfloat162 b01 = __float22bfloat162_rn(p01);
        __hip_bfloat162 b23 = __float22bfloat162_rn(p23);
        uint2 w;
        w.x = *(unsigned*)&b01;
        w.y = *(unsigned*)&b23;
        *(uint2*)(Pb + (a * 16 + lr) * 144 + ((n * 32 + lk * 8) ^ sw)) = w;
      }
    asm volatile("s_waitcnt lgkmcnt(0)" ::: "memory");
    __builtin_amdgcn_sched_barrier(0);

    // O += P V ; lsum += P * ones
#pragma unroll
    for (int kb = 0; kb < 2; ++kb) {
      short8 pf0 = *(const short8*)(Pb + (0 * 16 + lr) * 144 + ((kb * 64 + lk * 16) ^ sw));
      short8 pf1 = *(const short8*)(Pb + (1 * 16 + lr) * 144 + ((kb * 64 + lk * 16) ^ sw));
#pragma unroll
      for (int nd = 0; nd < 4; ++nd) {
        short8 vf = *(const short8*)&Vtt[(size_t)(nd * 16 + lr) * T_ + kb * 32 + lk * 8];
        o[0][nd] = MFMA_BF16(pf0, vf, o[0][nd]);
        o[1][nd] = MFMA_BF16(pf1, vf, o[1][nd]);
      }
      lsum[0] = MFMA_BF16(pf0, vones, lsum[0]);
      lsum[1] = MFMA_BF16(pf1, vones, lsum[1]);
    }
  }

  const int b = bh >> 4, h = bh & 15;
#pragma unroll
  for (int a = 0; a < 2; ++a)
#pragma unroll
    for (int r = 0; r < 4; ++r) {
      float inv = 1.0f / lsum[a][r];
      int t = q0 + a * 16 + lk * 4 + r;
#pragma unroll
      for (int nd = 0; nd < 4; ++nd)
        ctx[((size_t)b * T_ + t) * E_ + h * D_ + nd * 16 + lr] = f2bf(o[a][nd][r] * inv);
    }
}

// ---------------- launcher ----------------
extern "C" void kernel_launch(void* const* d_in, const int* in_sizes, int n_in,
                              void* d_out, int out_size, void* d_ws, size_t ws_size,
                              hipStream_t stream) {
  const float* x    = (const float*)d_in[0];
  const float* Wq   = (const float*)d_in[1];
  const float* Wk   = (const float*)d_in[2];
  const float* Wv   = (const float*)d_in[3];
  const float* Wout = (const float*)d_in[4];
  const float* bout = (const float*)d_in[5];
  float* out = (float*)d_out;

  const size_t MT = (size_t)B_ * T_;      // 8192
  const size_t XE = MT * E_;              // 8,388,608
  const size_t WE = (size_t)E_ * E_;      // 1,048,576

  size_t need = (XE * 5 + WE * 4) * sizeof(unsigned short);
  if (ws_size < need) return;

  unsigned short* xb  = (unsigned short*)d_ws;
  unsigned short* wqb = xb + XE;
  unsigned short* wkb = wqb + WE;
  unsigned short* wvb = wkb + WE;
  unsigned short* wob = wvb + WE;
  unsigned short* Qb  = wob + WE;
  unsigned short* Kb  = Qb + XE;
  unsigned short* VTb = Kb + XE;
  unsigned short* ctx = VTb + XE;

  cvt_f32_bf16<<<(int)(XE / 8 / 256), 256, 0, stream>>>(x, xb, (int)(XE / 8));
  cvt_w4<<<2048, 256, 0, stream>>>(Wq, Wk, Wv, Wout, wqb);

  gemm_qkv<<<dim3(MT / 128, 24), 256, 0, stream>>>(xb, wqb, wkb, wvb, Qb, Kb, ctx);

  transpose_v<<<dim3(T_ / 64, B_ * H_), 256, 0, stream>>>(ctx, VTb);

  attn_fused<<<1024, 256, 0, stream>>>(Qb, Kb, VTb, ctx);

  gemm_out<<<dim3(MT / 128, E_ / 128), 256, 0, stream>>>(ctx, wob, out, bout, (int)MT, E_, E_);
}

// Round 5
// 254.327 us; speedup vs baseline: 2.1163x; 1.0067x over previous
//
#include <hip/hip_runtime.h>
#include <hip/hip_bf16.h>
#include <stdint.h>
#include <math.h>

#define B_ 4
#define T_ 2048
#define E_ 1024
#define H_ 16
#define D_ 64

typedef __attribute__((ext_vector_type(8))) short short8;
typedef __attribute__((ext_vector_type(4))) float f32x4;

#define MFMA_BF16(a, b, c) __builtin_amdgcn_mfma_f32_16x16x32_bf16((a), (b), (c), 0, 0, 0)

__device__ __forceinline__ unsigned short f2bf(float f) {
  union { float f; unsigned u; } v; v.f = f;
  unsigned r = v.u + 0x7FFFu + ((v.u >> 16) & 1u);  // RNE
  return (unsigned short)(r >> 16);
}

#define GLOAD_LDS16(g, l)                                                        \
  __builtin_amdgcn_global_load_lds((const __attribute__((address_space(1))) void*)(g), \
                                   (__attribute__((address_space(3))) void*)(l), 16, 0, 0)

// ---------------- fp32 -> bf16 convert (vectorized) ----------------
__global__ __launch_bounds__(256) void cvt_f32_bf16(const float* __restrict__ in,
                                                    unsigned short* __restrict__ out,
                                                    int n8) {
  int i = blockIdx.x * blockDim.x + threadIdx.x;
  if (i >= n8) return;
  const float4* p = (const float4*)(in + (size_t)i * 8);
  float4 a = p[0], b = p[1];
  short8 r;
  r[0] = (short)f2bf(a.x); r[1] = (short)f2bf(a.y);
  r[2] = (short)f2bf(a.z); r[3] = (short)f2bf(a.w);
  r[4] = (short)f2bf(b.x); r[5] = (short)f2bf(b.y);
  r[6] = (short)f2bf(b.z); r[7] = (short)f2bf(b.w);
  *(short8*)(out + (size_t)i * 8) = r;
}

// 4 weight matrices in one launch (dest regions contiguous in ws)
__global__ __launch_bounds__(256) void cvt_w4(const float* __restrict__ w0,
                                              const float* __restrict__ w1,
                                              const float* __restrict__ w2,
                                              const float* __restrict__ w3,
                                              unsigned short* __restrict__ out) {
  int i = blockIdx.x * blockDim.x + threadIdx.x;  // one per 8 elems
  int which = i >> 17;                            // WE/8 = 2^17
  int off = i & 131071;
  const float* src = (which == 0) ? w0 : (which == 1) ? w1 : (which == 2) ? w2 : w3;
  const float4* p = (const float4*)(src + (size_t)off * 8);
  float4 a = p[0], b = p[1];
  short8 r;
  r[0] = (short)f2bf(a.x); r[1] = (short)f2bf(a.y);
  r[2] = (short)f2bf(a.z); r[3] = (short)f2bf(a.w);
  r[4] = (short)f2bf(b.x); r[5] = (short)f2bf(b.y);
  r[6] = (short)f2bf(b.z); r[7] = (short)f2bf(b.w);
  *(short8*)(out + ((size_t)which << 20) + (size_t)off * 8) = r;
}

// ---------------- fused QKV GEMM: C = x * W^T for W in {Wq,Wk,Wv} -------------
__global__ __launch_bounds__(256) void gemm_qkv(const unsigned short* __restrict__ A,
                                                const unsigned short* __restrict__ Wq,
                                                const unsigned short* __restrict__ Wk,
                                                const unsigned short* __restrict__ Wv,
                                                unsigned short* __restrict__ Qo,
                                                unsigned short* __restrict__ Ko,
                                                unsigned short* __restrict__ Vo) {
  __shared__ __align__(16) unsigned short Ab[128 * 64];
  __shared__ __align__(16) unsigned short Bb[128 * 64];
  const int K = E_;
  const int tid = threadIdx.x;
  const int wid = tid >> 6;
  const int lr = tid & 15;
  const int lk = (tid >> 4) & 3;
  const int wr = wid >> 1, wc = wid & 1;
  const int m0 = blockIdx.x * 128;
  const int sel = blockIdx.y >> 3;
  const int n0 = (blockIdx.y & 7) * 128;
  const unsigned short* Bm = (sel == 0) ? Wq : (sel == 1) ? Wk : Wv;
  unsigned short* outp = (sel == 0) ? Qo : (sel == 1) ? Ko : Vo;

  f32x4 acc[4][4] = {};

  for (int k0 = 0; k0 < K; k0 += 64) {
    __syncthreads();
#pragma unroll
    for (int pass = 0; pass < 4; ++pass) {
      int chunk = pass * 256 + tid;
      int row = chunk >> 3, inner = chunk & 7;
      const unsigned short* ga = A + (size_t)(m0 + row) * K + k0 + inner * 8;
      const unsigned short* gb = Bm + (size_t)(n0 + row) * K + k0 + inner * 8;
      unsigned short* la = Ab + (size_t)(pass * 256 + wid * 64) * 8;
      unsigned short* lb = Bb + (size_t)(pass * 256 + wid * 64) * 8;
      GLOAD_LDS16(ga, la);
      GLOAD_LDS16(gb, lb);
    }
    __syncthreads();
#pragma unroll
    for (int kk = 0; kk < 2; ++kk) {
      short8 af[4], bf[4];
#pragma unroll
      for (int mi = 0; mi < 4; ++mi)
        af[mi] = *(const short8*)&Ab[(wr * 64 + mi * 16 + lr) * 64 + kk * 32 + lk * 8];
#pragma unroll
      for (int ni = 0; ni < 4; ++ni)
        bf[ni] = *(const short8*)&Bb[(wc * 64 + ni * 16 + lr) * 64 + kk * 32 + lk * 8];
#pragma unroll
      for (int mi = 0; mi < 4; ++mi)
#pragma unroll
        for (int ni = 0; ni < 4; ++ni)
          acc[mi][ni] = MFMA_BF16(af[mi], bf[ni], acc[mi][ni]);
    }
  }

#pragma unroll
  for (int mi = 0; mi < 4; ++mi)
#pragma unroll
    for (int ni = 0; ni < 4; ++ni)
#pragma unroll
      for (int r = 0; r < 4; ++r) {
        int row = m0 + wr * 64 + mi * 16 + lk * 4 + r;
        int col = n0 + wc * 64 + ni * 16 + lr;
        int b = row >> 11, t = row & (T_ - 1), h = col >> 6, d = col & (D_ - 1);
        outp[(((size_t)(b * H_ + h)) * T_ + t) * D_ + d] = f2bf(acc[mi][ni][r]);
      }
}

// ---------------- out-proj GEMM: fp32 out + bias ----------------
__global__ __launch_bounds__(256) void gemm_out(const unsigned short* __restrict__ A,
                                                const unsigned short* __restrict__ Bm,
                                                float* __restrict__ outp,
                                                const float* __restrict__ bias,
                                                int M, int N, int K) {
  __shared__ __align__(16) unsigned short Ab[128 * 64];
  __shared__ __align__(16) unsigned short Bb[128 * 64];
  const int tid = threadIdx.x;
  const int wid = tid >> 6;
  const int lr = tid & 15;
  const int lk = (tid >> 4) & 3;
  const int wr = wid >> 1, wc = wid & 1;
  const int m0 = blockIdx.x * 128, n0 = blockIdx.y * 128;

  f32x4 acc[4][4] = {};

  for (int k0 = 0; k0 < K; k0 += 64) {
    __syncthreads();
#pragma unroll
    for (int pass = 0; pass < 4; ++pass) {
      int chunk = pass * 256 + tid;
      int row = chunk >> 3, inner = chunk & 7;
      const unsigned short* ga = A + (size_t)(m0 + row) * K + k0 + inner * 8;
      const unsigned short* gb = Bm + (size_t)(n0 + row) * K + k0 + inner * 8;
      unsigned short* la = Ab + (size_t)(pass * 256 + wid * 64) * 8;
      unsigned short* lb = Bb + (size_t)(pass * 256 + wid * 64) * 8;
      GLOAD_LDS16(ga, la);
      GLOAD_LDS16(gb, lb);
    }
    __syncthreads();
#pragma unroll
    for (int kk = 0; kk < 2; ++kk) {
      short8 af[4], bf[4];
#pragma unroll
      for (int mi = 0; mi < 4; ++mi)
        af[mi] = *(const short8*)&Ab[(wr * 64 + mi * 16 + lr) * 64 + kk * 32 + lk * 8];
#pragma unroll
      for (int ni = 0; ni < 4; ++ni)
        bf[ni] = *(const short8*)&Bb[(wc * 64 + ni * 16 + lr) * 64 + kk * 32 + lk * 8];
#pragma unroll
      for (int mi = 0; mi < 4; ++mi)
#pragma unroll
        for (int ni = 0; ni < 4; ++ni)
          acc[mi][ni] = MFMA_BF16(af[mi], bf[ni], acc[mi][ni]);
    }
  }

#pragma unroll
  for (int mi = 0; mi < 4; ++mi)
#pragma unroll
    for (int ni = 0; ni < 4; ++ni)
#pragma unroll
      for (int r = 0; r < 4; ++r) {
        int row = m0 + wr * 64 + mi * 16 + lk * 4 + r;
        int col = n0 + wc * 64 + ni * 16 + lr;
        outp[(size_t)row * N + col] = acc[mi][ni][r] + bias[col];
      }
}

// ---------------- V transpose: [BH][T][D] -> [BH][D][T] ----------------
__global__ __launch_bounds__(256) void transpose_v(const unsigned short* __restrict__ V,
                                                   unsigned short* __restrict__ VT) {
  const int lane = threadIdx.x & 63;
  const int w = threadIdx.x >> 6;
  const int tb = blockIdx.x * 64;
  const int bh = blockIdx.y;
  const unsigned short* Vh = V + (size_t)bh * T_ * D_;
  unsigned short* Vo = VT + (size_t)bh * T_ * D_;
  short8 v0, v1;
#pragma unroll
  for (int j = 0; j < 8; ++j)
    v0[j] = (short)Vh[(size_t)(tb + w * 16 + j) * D_ + lane];
#pragma unroll
  for (int j = 0; j < 8; ++j)
    v1[j] = (short)Vh[(size_t)(tb + w * 16 + 8 + j) * D_ + lane];
  *(short8*)&Vo[(size_t)lane * T_ + tb + w * 16] = v0;
  *(short8*)&Vo[(size_t)lane * T_ + tb + w * 16 + 8] = v1;
}

// ---------------- fused causal flash attention (swapped QK^T) ----------------
// 4096 blocks x 64 thr (1 wave): one 32-row q-chunk each. No barriers.
// S^T = mfma(K,Q): full q-column per lane -> in-lane softmax (2 shuffles).
// P round-trip via stride-144B LDS rows (NO xor swizzle: stride already
// rotates banks; quarter-wave analysis = 2-way = free). V fragments
// prefetched into regs before softmax so L2 latency hides under it.
__global__ __launch_bounds__(64) void attn_fused(const unsigned short* __restrict__ Q,
                                                 const unsigned short* __restrict__ K,
                                                 const unsigned short* __restrict__ VT,
                                                 unsigned short* __restrict__ ctx) {
  __shared__ __align__(16) unsigned short Pl[32 * 72];  // 32 rows x 144 B
  const int tid = threadIdx.x;
  const int lane = tid & 63;
  const int lr = lane & 15;
  const int lk = lane >> 4;

  // XCD swizzle: 8 heads/XCD; heaviest chunks dispatched first.
  const int bid = blockIdx.x;
  const int xcd = bid & 7;
  const int p = bid >> 3;           // 0..511 per XCD
  const int chunk = 63 - (p >> 3);  // heavy first
  const int bh = xcd * 8 + (p & 7);
  const int q0 = chunk * 32;

  const unsigned short* Qh = Q + (size_t)bh * T_ * D_;
  const unsigned short* Kh = K + (size_t)bh * T_ * D_;
  const unsigned short* Vh = VT + (size_t)bh * T_ * D_;  // [D][T]
  char* Pb = (char*)Pl;

  const float SC = 0.125f * 1.44269504089f;  // 1/sqrt(D) * log2(e)

  short8 vones;
#pragma unroll
  for (int j = 0; j < 8; ++j) vones[j] = (short)0x3F80;  // bf16 1.0

  // Q as B-operand: col=q=lr, k=d
  short8 qf[2][2];
#pragma unroll
  for (int a = 0; a < 2; ++a)
#pragma unroll
    for (int kb = 0; kb < 2; ++kb)
      qf[a][kb] = *(const short8*)&Qh[(size_t)(q0 + a * 16 + lr) * D_ + kb * 32 + lk * 8];

  f32x4 o[2][4] = {};
  f32x4 lsum[2] = {};
  float mrun[2] = {-1e30f, -1e30f};

  const int nt = (q0 >> 6) + 1;
  const int ql0 = (q0 & 63);  // q-local base within diag tile

  for (int kvt = 0; kvt < nt; ++kvt) {
    const unsigned short* Kt = Kh + (size_t)kvt * 64 * D_;
    const unsigned short* Vtt = Vh + (size_t)kvt * 64;

    // K fragments (issued first; QK waits on these only)
    short8 kf[2][4];
#pragma unroll
    for (int kb = 0; kb < 2; ++kb)
#pragma unroll
      for (int n = 0; n < 4; ++n)
        kf[kb][n] = *(const short8*)&Kt[(size_t)(n * 16 + lr) * D_ + kb * 32 + lk * 8];

    // V fragments prefetch (in flight through softmax; consumed in PV)
    short8 vreg[2][4];
#pragma unroll
    for (int kb = 0; kb < 2; ++kb)
#pragma unroll
      for (int nd = 0; nd < 4; ++nd)
        vreg[kb][nd] = *(const short8*)&Vtt[(size_t)(nd * 16 + lr) * T_ + kb * 32 + lk * 8];

    // S^T = K Q^T : row=kv (n*16+lk*4+r), col=q (lr)
    f32x4 st[2][4] = {};
#pragma unroll
    for (int kb = 0; kb < 2; ++kb)
#pragma unroll
      for (int a = 0; a < 2; ++a)
#pragma unroll
        for (int n = 0; n < 4; ++n)
          st[a][n] = MFMA_BF16(kf[kb][n], qf[a][kb], st[a][n]);

    if (kvt == nt - 1) {  // diagonal tile: mask kv_local > q_local
#pragma unroll
      for (int a = 0; a < 2; ++a)
#pragma unroll
        for (int n = 0; n < 4; ++n)
#pragma unroll
          for (int r = 0; r < 4; ++r)
            if (n * 16 + lk * 4 + r > ql0 + a * 16 + lr) st[a][n][r] = -3e38f;
    }

    // row max: 2-level tree (max3-fusable) + 2 shuffles across lk-groups
    float pm[2];
#pragma unroll
    for (int a = 0; a < 2; ++a) {
      float m0 = fmaxf(fmaxf(st[a][0][0], st[a][1][0]), fmaxf(st[a][2][0], st[a][3][0]));
      float m1 = fmaxf(fmaxf(st[a][0][1], st[a][1][1]), fmaxf(st[a][2][1], st[a][3][1]));
      float m2 = fmaxf(fmaxf(st[a][0][2], st[a][1][2]), fmaxf(st[a][2][2], st[a][3][2]));
      float m3 = fmaxf(fmaxf(st[a][0][3], st[a][1][3]), fmaxf(st[a][2][3], st[a][3][3]));
      float mx = fmaxf(fmaxf(m0, m1), fmaxf(m2, m3));
      mx = fmaxf(mx, __shfl_xor(mx, 16));
      mx = fmaxf(mx, __shfl_xor(mx, 32));
      pm[a] = mx * SC;
    }
    float need = fmaxf(pm[0] - mrun[0], pm[1] - mrun[1]);

    if (__any(need > 8.f)) {  // defer-max rescale (rare)
#pragma unroll
      for (int a = 0; a < 2; ++a) {
        float mnew = fmaxf(mrun[a], pm[a]);
        float sc = exp2f(mrun[a] - mnew);
        mrun[a] = mnew;
#pragma unroll
        for (int r = 0; r < 4; ++r) {
          float sco = __shfl(sc, (lane & 48) | (lk * 4 + r));
          lsum[a][r] *= sco;
#pragma unroll
          for (int nd = 0; nd < 4; ++nd) o[a][nd][r] *= sco;
        }
      }
    }

    // P = exp2(S*SC - m), packed bf16x4 -> LDS (8x ds_write_b64, stride 144)
#pragma unroll
    for (int a = 0; a < 2; ++a)
#pragma unroll
      for (int n = 0; n < 4; ++n) {
        float2 p01, p23;
        p01.x = exp2f(fmaf(st[a][n][0], SC, -mrun[a]));
        p01.y = exp2f(fmaf(st[a][n][1], SC, -mrun[a]));
        p23.x = exp2f(fmaf(st[a][n][2], SC, -mrun[a]));
        p23.y = exp2f(fmaf(st[a][n][3], SC, -mrun[a]));
        __hip_bfloat162 b01 = __float22bfloat162_rn(p01);
        __hip_bfloat162 b23 = __float22bfloat162_rn(p23);
        uint2 w;
        w.x = *(unsigned*)&b01;
        w.y = *(unsigned*)&b23;
        *(uint2*)(Pb + (a * 16 + lr) * 144 + n * 32 + lk * 8) = w;
      }
    asm volatile("s_waitcnt lgkmcnt(0)" ::: "memory");
    __builtin_amdgcn_sched_barrier(0);

    // O += P V ; lsum += P * ones (V already in regs)
#pragma unroll
    for (int kb = 0; kb < 2; ++kb) {
      short8 pf0 = *(const short8*)(Pb + (0 * 16 + lr) * 144 + kb * 64 + lk * 16);
      short8 pf1 = *(const short8*)(Pb + (1 * 16 + lr) * 144 + kb * 64 + lk * 16);
#pragma unroll
      for (int nd = 0; nd < 4; ++nd) {
        o[0][nd] = MFMA_BF16(pf0, vreg[kb][nd], o[0][nd]);
        o[1][nd] = MFMA_BF16(pf1, vreg[kb][nd], o[1][nd]);
      }
      lsum[0] = MFMA_BF16(pf0, vones, lsum[0]);
      lsum[1] = MFMA_BF16(pf1, vones, lsum[1]);
    }
  }

  const int b = bh >> 4, h = bh & 15;
#pragma unroll
  for (int a = 0; a < 2; ++a)
#pragma unroll
    for (int r = 0; r < 4; ++r) {
      float inv = 1.0f / lsum[a][r];
      int t = q0 + a * 16 + lk * 4 + r;
#pragma unroll
      for (int nd = 0; nd < 4; ++nd)
        ctx[((size_t)b * T_ + t) * E_ + h * D_ + nd * 16 + lr] = f2bf(o[a][nd][r] * inv);
    }
}

// ---------------- launcher ----------------
extern "C" void kernel_launch(void* const* d_in, const int* in_sizes, int n_in,
                              void* d_out, int out_size, void* d_ws, size_t ws_size,
                              hipStream_t stream) {
  const float* x    = (const float*)d_in[0];
  const float* Wq   = (const float*)d_in[1];
  const float* Wk   = (const float*)d_in[2];
  const float* Wv   = (const float*)d_in[3];
  const float* Wout = (const float*)d_in[4];
  const float* bout = (const float*)d_in[5];
  float* out = (float*)d_out;

  const size_t MT = (size_t)B_ * T_;      // 8192
  const size_t XE = MT * E_;              // 8,388,608
  const size_t WE = (size_t)E_ * E_;      // 1,048,576

  size_t need = (XE * 5 + WE * 4) * sizeof(unsigned short);
  if (ws_size < need) return;

  unsigned short* xb  = (unsigned short*)d_ws;
  unsigned short* wqb = xb + XE;
  unsigned short* wkb = wqb + WE;
  unsigned short* wvb = wkb + WE;
  unsigned short* wob = wvb + WE;
  unsigned short* Qb  = wob + WE;
  unsigned short* Kb  = Qb + XE;
  unsigned short* VTb = Kb + XE;
  unsigned short* ctx = VTb + XE;

  cvt_f32_bf16<<<(int)(XE / 8 / 256), 256, 0, stream>>>(x, xb, (int)(XE / 8));
  cvt_w4<<<2048, 256, 0, stream>>>(Wq, Wk, Wv, Wout, wqb);

  gemm_qkv<<<dim3(MT / 128, 24), 256, 0, stream>>>(xb, wqb, wkb, wvb, Qb, Kb, ctx);

  transpose_v<<<dim3(T_ / 64, B_ * H_), 256, 0, stream>>>(ctx, VTb);

  attn_fused<<<4096, 64, 0, stream>>>(Qb, Kb, VTb, ctx);

  gemm_out<<<dim3(MT / 128, E_ / 128), 256, 0, stream>>>(ctx, wob, out, bout, (int)MT, E_, E_);
}